// Round 4
// baseline (411.830 us; speedup 1.0000x reference)
//
#include <hip/hip_runtime.h>
#include <stdint.h>

// MX fp8-e4m3 block quantize-dequantize, BLOCK=32 along last dim. Bit-exact
// vs the jax/numpy reference (absmax 0.0, rounds 1 & 3).
//
// Layout: one wave (64 lanes) owns 1024 contiguous elements as four perfectly
// coalesced 16B/lane chunks (each global_load_dwordx4 covers a dense 1KB).
// 32-elem quant blocks == 8-lane groups; amax via 3 shfl_xor per chunk.
// 16 elems/thread: 4 loads in flight (MLP probe vs round-3's 2).

typedef float f32x4 __attribute__((ext_vector_type(4)));

__device__ __forceinline__ float bf16_rne(float x) {
    // round-to-nearest-even f32 -> bf16 -> f32 (finite inputs)
    uint32_t u = __float_as_uint(x);
    u = (u + 0x7fffu + ((u >> 16) & 1u)) & 0xffff0000u;
    return __uint_as_float(u);
}

__device__ __forceinline__ float block_scale(float m) {
    // scales = bf16(amax/448); nano-mantissa round at 8 bits (bf16 math);
    // zero -> 1.0
    float sb = bf16_rne(m / 448.0f);
    float t  = sb * 256.0f;                  // exact pow2 scaling
    float r  = floorf(bf16_rne(t + 0.5f));   // round half away (t >= 0)
    float s  = r * 0.00390625f;              // /256, exact
    return (s == 0.0f) ? 1.0f : s;
}

__device__ __forceinline__ float quant_one(float x, float s) {
    float v  = x / s;                        // IEEE f32 div (exactness matters)
    float av = fabsf(v);
    // floor(log2|v|) via exponent field; zero/denorm -> -127 -> clamped to -6,
    // matching the reference's max(private_exp, -6).
    int e = (int)(__float_as_uint(av) >> 23) - 127;
    if (e < -6) e = -6;
    float q  = ldexpf(v, 3 - e);                 // v / 2^e * 8   (exact)
    float rq = floorf(fabsf(q) + 0.5f);          // round half away from zero
    float o  = ldexpf(copysignf(rq, v), e - 3);  // rq / 8 * 2^e  (exact)
    o = fminf(fmaxf(o, -448.0f), 448.0f);        // saturate_normals
    o = (av <= 3.402823466e+38f) ? o : v;        // Inf/NaN passthrough
    return o * s;
}

__device__ __forceinline__ float amax4(f32x4 a) {
    return fmaxf(fmaxf(fabsf(a.x), fabsf(a.y)), fmaxf(fabsf(a.z), fabsf(a.w)));
}

__device__ __forceinline__ f32x4 quant4(f32x4 a, float s) {
    f32x4 r;
    r.x = quant_one(a.x, s);
    r.y = quant_one(a.y, s);
    r.z = quant_one(a.z, s);
    r.w = quant_one(a.w, s);
    return r;
}

__global__ __launch_bounds__(256) void MXQuantizer_kernel(
        const float* __restrict__ in, float* __restrict__ out, long long n) {
    long long tid  = (long long)blockIdx.x * blockDim.x + threadIdx.x;
    long long wave = tid >> 6;
    int lane = (int)(threadIdx.x & 63);
    long long base = wave * 1024 + (long long)lane * 4;
    if (base >= n) return;  // n is a multiple of 1024 (8192x8192)

    f32x4 v[4];
#pragma unroll
    for (int c = 0; c < 4; ++c)
        v[c] = __builtin_nontemporal_load(
            reinterpret_cast<const f32x4*>(in + base + c * 256));

    // per-block (32 elems = 8 lanes x 4) amax via butterfly over lane bits 0..2
    float m[4];
#pragma unroll
    for (int c = 0; c < 4; ++c) m[c] = amax4(v[c]);
#pragma unroll
    for (int mask = 1; mask <= 4; mask <<= 1)
#pragma unroll
        for (int c = 0; c < 4; ++c)
            m[c] = fmaxf(m[c], __shfl_xor(m[c], mask, 64));

    f32x4 o[4];
#pragma unroll
    for (int c = 0; c < 4; ++c) o[c] = quant4(v[c], block_scale(m[c]));

#pragma unroll
    for (int c = 0; c < 4; ++c)
        __builtin_nontemporal_store(
            o[c], reinterpret_cast<f32x4*>(out + base + c * 256));
}

extern "C" void kernel_launch(void* const* d_in, const int* in_sizes, int n_in,
                              void* d_out, int out_size, void* d_ws, size_t ws_size,
                              hipStream_t stream) {
    const float* in = (const float*)d_in[0];
    float* out = (float*)d_out;
    long long n = (long long)in_sizes[0];      // 8192*8192, multiple of 1024
    long long threads = n / 16;                // 16 elems per thread
    int block = 256;
    unsigned grid = (unsigned)((threads + block - 1) / block);
    MXQuantizer_kernel<<<grid, block, 0, stream>>>(in, out, n);
}